// Round 1
// baseline (353.690 us; speedup 1.0000x reference)
//
#include <hip/hip_runtime.h>
#include <math.h>

#define NPROT 50000
#define FDIM 128
#define HDIM 256
#define EPPI 500000
#define NPAIR 4096

typedef __attribute__((ext_vector_type(8))) __bf16 bf16x8;
typedef __attribute__((ext_vector_type(4))) float floatx4;

// ---------- CSR build ----------
__global__ void k_zero(int* cnt) {
    int i = blockIdx.x * 256 + threadIdx.x;
    if (i < NPROT) cnt[i] = 0;
}

__global__ void k_hist(const int* __restrict__ dst, int* __restrict__ cnt) {
    int e = blockIdx.x * 256 + threadIdx.x;
    if (e < EPPI) atomicAdd(&cnt[dst[e]], 1);
}

__global__ void k_scan1(const int* __restrict__ cnt, int* __restrict__ rowptr,
                        int* __restrict__ blocksum) {
    __shared__ int sd[1024];
    int t = threadIdx.x;
    int i = blockIdx.x * 1024 + t;
    int v = (i < NPROT) ? cnt[i] : 0;
    sd[t] = v;
    __syncthreads();
    int x = v;
    for (int off = 1; off < 1024; off <<= 1) {
        int add = (t >= off) ? sd[t - off] : 0;
        __syncthreads();
        x += add;
        sd[t] = x;
        __syncthreads();
    }
    if (i < NPROT) rowptr[i] = x - v;   // block-local exclusive
    if (t == 1023) blocksum[blockIdx.x] = x;
}

__global__ void k_scan2(int* blocksum, int nb) {
    if (threadIdx.x == 0 && blockIdx.x == 0) {
        int run = 0;
        for (int b = 0; b < nb; b++) { int t = blocksum[b]; blocksum[b] = run; run += t; }
    }
}

__global__ void k_scan3(const int* __restrict__ cnt, int* __restrict__ rowptr,
                        int* __restrict__ cursor, float* __restrict__ inv,
                        const int* __restrict__ blocksum) {
    int t = threadIdx.x;
    int i = blockIdx.x * 1024 + t;
    if (i < NPROT) {
        int r = rowptr[i] + blocksum[blockIdx.x];
        rowptr[i] = r;
        cursor[i] = r;
        int c = cnt[i];
        inv[i] = 1.0f / (float)(c > 1 ? c : 1);
        if (i == NPROT - 1) rowptr[NPROT] = r + c;
    }
}

__global__ void k_fill(const int* __restrict__ src, const int* __restrict__ dst,
                       int* __restrict__ cursor, int* __restrict__ ssrc) {
    int e = blockIdx.x * 256 + threadIdx.x;
    if (e < EPPI) {
        int d = dst[e];
        int p = atomicAdd(&cursor[d], 1);
        ssrc[p] = src[e];
    }
}

// ---------- weight prep ----------
// Bw[h][k] (256x256, k contiguous): k<128 -> aWl[h][k], else aWr[h][k-128]   (bf16)
__global__ void k_wb(const float* __restrict__ Wl, const float* __restrict__ Wr,
                     __bf16* __restrict__ Bw) {
    int idx = blockIdx.x * 256 + threadIdx.x;  // 65536
    int h = idx >> 8, k = idx & 255;
    float v = (k < 128) ? Wl[h * 128 + k] : Wr[h * 128 + (k - 128)];
    Bw[idx] = (__bf16)v;
}

// P[h][0..3] = {v1,v2,u1,u2}; biasC = w1·bb + w2·bb + lin_b
__global__ void k_setup(const float* __restrict__ linW, const float* __restrict__ linb,
                        const float* __restrict__ bWl, const float* __restrict__ bWr,
                        const float* __restrict__ bb, float* __restrict__ P,
                        float* __restrict__ biasC) {
    int h = threadIdx.x;  // 256
    float v1 = 0, v2 = 0, u1 = 0, u2 = 0;
    for (int f = 0; f < 128; f++) {
        float w1 = linW[f], w2 = linW[128 + f];
        float wl = bWl[f * 256 + h], wr = bWr[f * 256 + h];
        v1 += w1 * wl; v2 += w2 * wl; u1 += w1 * wr; u2 += w2 * wr;
    }
    P[h * 4 + 0] = v1; P[h * 4 + 1] = v2; P[h * 4 + 2] = u1; P[h * 4 + 3] = u2;
    if (h == 0) {
        float c = linb[0];
        for (int f = 0; f < 128; f++) c += (linW[f] + linW[128 + f]) * bb[f];
        *biasC = c;
    }
}

// ---------- layer-1 neighbor mean + pack A = [mean | x] as bf16 ----------
__global__ void k_agg(const float* __restrict__ x, const int* __restrict__ rowptr,
                      const int* __restrict__ ssrc, const float* __restrict__ inv,
                      __bf16* __restrict__ A) {
    int wave = threadIdx.x >> 6, lane = threadIdx.x & 63;
    int node = blockIdx.x * 4 + wave;
    if (node >= NPROT) return;
    int b0 = rowptr[node], b1 = rowptr[node + 1];
    float ax = 0.f, ay = 0.f;
    const float* xf = x + lane * 2;
    for (int j = b0; j < b1; j++) {
        int s = ssrc[j];
        float2 v = *(const float2*)(xf + (size_t)s * 128);
        ax += v.x; ay += v.y;
    }
    float iv = inv[node];
    ax *= iv; ay *= iv;
    __bf16* Ar = A + (size_t)node * 256;
    Ar[lane * 2 + 0] = (__bf16)ax;
    Ar[lane * 2 + 1] = (__bf16)ay;
    float2 own = *(const float2*)(x + (size_t)node * 128 + lane * 2);
    Ar[128 + lane * 2 + 0] = (__bf16)own.x;
    Ar[128 + lane * 2 + 1] = (__bf16)own.y;
}

// ---------- GEMM z = A @ Bw^T (+ab), relu, project onto P -> y[node][4] ----------
// A: 50000x256 bf16 (k contiguous), Bw: 256x256 bf16 (k contiguous)
// Block: 256 threads = 4 waves, each wave computes 16 rows x 256 cols.
__global__ __launch_bounds__(256) void k_gemm(const __bf16* __restrict__ A,
                                              const __bf16* __restrict__ Bw,
                                              const float* __restrict__ ab,
                                              const float* __restrict__ P,
                                              float* __restrict__ y) {
    int wave = threadIdx.x >> 6, lane = threadIdx.x & 63;
    int row0 = blockIdx.x * 64 + wave * 16;
    if (row0 >= NPROT) return;
    int r = lane & 15, quad = lane >> 4;

    floatx4 acc[16];
#pragma unroll
    for (int t = 0; t < 16; t++) acc[t] = (floatx4){0.f, 0.f, 0.f, 0.f};

    const __bf16* Abase = A + (size_t)(row0 + r) * 256 + quad * 8;
    const __bf16* Bbase = Bw + (size_t)r * 256 + quad * 8;

    for (int kk = 0; kk < 8; kk++) {  // K = 256 in steps of 32
        bf16x8 af = *(const bf16x8*)(Abase + kk * 32);
#pragma unroll
        for (int t = 0; t < 16; t++) {
            bf16x8 bf = *(const bf16x8*)(Bbase + (size_t)t * 16 * 256 + kk * 32);
            acc[t] = __builtin_amdgcn_mfma_f32_16x16x32_bf16(af, bf, acc[t], 0, 0, 0);
        }
    }

    // epilogue: h = relu(z + ab[col]); part[row][j] += h * P[col][j]
    float part[4][4] = {{0.f}};
#pragma unroll
    for (int t = 0; t < 16; t++) {
        int col = t * 16 + r;
        float bias = ab[col];
        float4 pv = *(const float4*)(P + col * 4);
#pragma unroll
        for (int rr = 0; rr < 4; rr++) {
            float h = acc[t][rr] + bias;
            h = h > 0.f ? h : 0.f;
            part[rr][0] += h * pv.x;
            part[rr][1] += h * pv.y;
            part[rr][2] += h * pv.z;
            part[rr][3] += h * pv.w;
        }
    }
    // reduce over the 16 lanes of the same quad (cols)
#pragma unroll
    for (int m = 1; m < 16; m <<= 1) {
#pragma unroll
        for (int rr = 0; rr < 4; rr++)
#pragma unroll
            for (int j = 0; j < 4; j++)
                part[rr][j] += __shfl_xor(part[rr][j], m, 64);
    }
    if (r == 0) {
#pragma unroll
        for (int rr = 0; rr < 4; rr++) {
            int row = row0 + quad * 4 + rr;
            float4 o;
            o.x = part[rr][0]; o.y = part[rr][1]; o.z = part[rr][2]; o.w = part[rr][3];
            *(float4*)(y + (size_t)row * 4) = o;
        }
    }
}

// ---------- head: per masked node, CSR-sum scalar projections ----------
__global__ void k_head(const int* __restrict__ mask, const int* __restrict__ rowptr,
                       const int* __restrict__ ssrc, const float* __restrict__ inv,
                       const float* __restrict__ y, const float* __restrict__ biasC,
                       float* __restrict__ out) {
    int tid = blockIdx.x * 256 + threadIdx.x;
    int p = tid >> 1, side = tid & 1;
    float res = 0.f;
    if (p < NPAIR) {
        int node = mask[p * 2 + side];
        int b0 = rowptr[node], b1 = rowptr[node + 1];
        float s = 0.f;
        for (int j = b0; j < b1; j++) s += y[(size_t)ssrc[j] * 4 + side];
        res = s * inv[node] + y[(size_t)node * 4 + 2 + side];
    }
    float other = __shfl_xor(res, 1, 64);
    if (p < NPAIR && side == 0) {
        float z = res + other + *biasC;
        out[p] = 1.f / (1.f + expf(-z));
    }
}

extern "C" void kernel_launch(void* const* d_in, const int* in_sizes, int n_in,
                              void* d_out, int out_size, void* d_ws, size_t ws_size,
                              hipStream_t stream) {
    const float* x_protein = (const float*)d_in[0];
    const float* a_ppi_Wl  = (const float*)d_in[11];
    const float* a_ppi_b   = (const float*)d_in[12];
    const float* a_ppi_Wr  = (const float*)d_in[13];
    const float* b_ppi_Wl  = (const float*)d_in[23];
    const float* b_ppi_b   = (const float*)d_in[24];
    const float* b_ppi_Wr  = (const float*)d_in[25];
    const float* lin_W     = (const float*)d_in[26];
    const float* lin_b     = (const float*)d_in[27];
    const int* ppi_src     = (const int*)d_in[34];
    const int* ppi_dst     = (const int*)d_in[35];
    const int* mask        = (const int*)d_in[36];
    float* out = (float*)d_out;

    char* ws = (char*)d_ws;
    size_t o = 0;
    auto alloc = [&](size_t n) -> char* {
        char* r = ws + o;
        o = (o + n + 511) & ~(size_t)511;
        return r;
    };
    int*    cnt      = (int*)alloc((size_t)NPROT * 4);
    int*    rowptr   = (int*)alloc((size_t)(NPROT + 1) * 4);
    int*    cursor   = (int*)alloc((size_t)NPROT * 4);
    int*    blocksum = (int*)alloc(64 * 4);
    float*  inv      = (float*)alloc((size_t)NPROT * 4);
    int*    ssrc     = (int*)alloc((size_t)EPPI * 4);
    __bf16* A        = (__bf16*)alloc((size_t)NPROT * 256 * 2);
    __bf16* Bw       = (__bf16*)alloc(256 * 256 * 2);
    float*  P        = (float*)alloc(256 * 4 * 4);
    float*  biasC    = (float*)alloc(4);
    float*  y        = (float*)alloc((size_t)NPROT * 4 * 4);
    (void)ws_size;

    int nb = (NPROT + 1023) / 1024;  // 49

    k_zero<<<(NPROT + 255) / 256, 256, 0, stream>>>(cnt);
    k_hist<<<(EPPI + 255) / 256, 256, 0, stream>>>(ppi_dst, cnt);
    k_scan1<<<nb, 1024, 0, stream>>>(cnt, rowptr, blocksum);
    k_scan2<<<1, 64, 0, stream>>>(blocksum, nb);
    k_scan3<<<nb, 1024, 0, stream>>>(cnt, rowptr, cursor, inv, blocksum);
    k_fill<<<(EPPI + 255) / 256, 256, 0, stream>>>(ppi_src, ppi_dst, cursor, ssrc);
    k_wb<<<256, 256, 0, stream>>>(a_ppi_Wl, a_ppi_Wr, Bw);
    k_setup<<<1, 256, 0, stream>>>(lin_W, lin_b, b_ppi_Wl, b_ppi_Wr, b_ppi_b, P, biasC);
    k_agg<<<(NPROT + 3) / 4, 256, 0, stream>>>(x_protein, rowptr, ssrc, inv, A);
    k_gemm<<<(NPROT + 63) / 64, 256, 0, stream>>>(A, Bw, a_ppi_b, P, y);
    k_head<<<(2 * NPAIR + 255) / 256, 256, 0, stream>>>(mask, rowptr, ssrc, inv, y, biasC, out);
}

// Round 2
// 306.854 us; speedup vs baseline: 1.1526x; 1.1526x over previous
//
#include <hip/hip_runtime.h>
#include <math.h>

#define NPROT 50000
#define NPROT_PAD 50048
#define EPPI 500000
#define NPAIR 4096

typedef __attribute__((ext_vector_type(8))) __bf16 bf16x8;
typedef __attribute__((ext_vector_type(4))) __bf16 bf16x4;
typedef __attribute__((ext_vector_type(4))) float floatx4;

// ---------- CSR build ----------
__global__ void k_hist(const int* __restrict__ dst, int* __restrict__ cnt) {
    int e = blockIdx.x * 256 + threadIdx.x;
    if (e < EPPI) atomicAdd(&cnt[dst[e]], 1);
}

__global__ void k_scan1(const int* __restrict__ cnt, int* __restrict__ rowptr,
                        int* __restrict__ blocksum) {
    __shared__ int sd[1024];
    int t = threadIdx.x;
    int i = blockIdx.x * 1024 + t;
    int v = (i < NPROT) ? cnt[i] : 0;
    sd[t] = v;
    __syncthreads();
    int x = v;
    for (int off = 1; off < 1024; off <<= 1) {
        int add = (t >= off) ? sd[t - off] : 0;
        __syncthreads();
        x += add;
        sd[t] = x;
        __syncthreads();
    }
    if (i < NPROT) rowptr[i] = x - v;   // block-local exclusive
    if (t == 1023) blocksum[blockIdx.x] = x;
}

__global__ void k_scan2(int* blocksum, int nb) {
    if (threadIdx.x == 0 && blockIdx.x == 0) {
        int run = 0;
        for (int b = 0; b < nb; b++) { int t = blocksum[b]; blocksum[b] = run; run += t; }
    }
}

__global__ void k_scan3(const int* __restrict__ cnt, int* __restrict__ rowptr,
                        int* __restrict__ cursor, float* __restrict__ inv,
                        const int* __restrict__ blocksum) {
    int t = threadIdx.x;
    int i = blockIdx.x * 1024 + t;
    if (i < NPROT) {
        int r = rowptr[i] + blocksum[blockIdx.x];
        rowptr[i] = r;
        cursor[i] = r;
        int c = cnt[i];
        inv[i] = 1.0f / (float)(c > 1 ? c : 1);
        if (i == NPROT - 1) rowptr[NPROT] = r + c;
    }
}

__global__ void k_fill(const int* __restrict__ src, const int* __restrict__ dst,
                       int* __restrict__ cursor, int* __restrict__ ssrc) {
    int e = blockIdx.x * 256 + threadIdx.x;
    if (e < EPPI) {
        int d = dst[e];
        int p = atomicAdd(&cursor[d], 1);
        ssrc[p] = src[e];
    }
}

// ---------- fused prep: x->bf16 own-half of A, Bw build, P/biasC, zero cnt, zero y ----------
__global__ void k_prep(const float* __restrict__ x,
                       const float* __restrict__ Wl, const float* __restrict__ Wr,
                       const float* __restrict__ linW, const float* __restrict__ linb,
                       const float* __restrict__ bWl, const float* __restrict__ bWr,
                       const float* __restrict__ bb,
                       __bf16* __restrict__ A, __bf16* __restrict__ Bw,
                       float* __restrict__ P, float* __restrict__ biasC,
                       int* __restrict__ cnt, float* __restrict__ y) {
    int b = blockIdx.x, t = threadIdx.x;
    if (b < 6250) {
        // cast x rows into A[row][128..255]
        int i = b * 256 + t;              // float4 index over 50000*32
        int row = i >> 5, k4 = (i & 31) << 2;
        float4 v = *(const float4*)(x + (size_t)row * 128 + k4);
        bf16x4 o; o[0] = (__bf16)v.x; o[1] = (__bf16)v.y; o[2] = (__bf16)v.z; o[3] = (__bf16)v.w;
        *(bf16x4*)(A + (size_t)row * 256 + 128 + k4) = o;
    } else if (b < 6506) {
        // Bw[h][k]: k<128 -> aWl, else aWr  (bf16)
        int idx = (b - 6250) * 256 + t;   // 65536
        int h = idx >> 8, k = idx & 255;
        float v = (k < 128) ? Wl[h * 128 + k] : Wr[h * 128 + (k - 128)];
        Bw[idx] = (__bf16)v;
    } else if (b == 6506) {
        int h = t;  // 256
        float v1 = 0, v2 = 0, u1 = 0, u2 = 0;
        for (int f = 0; f < 128; f++) {
            float w1 = linW[f], w2 = linW[128 + f];
            float wl = bWl[f * 256 + h], wr = bWr[f * 256 + h];
            v1 += w1 * wl; v2 += w2 * wl; u1 += w1 * wr; u2 += w2 * wr;
        }
        P[h * 4 + 0] = v1; P[h * 4 + 1] = v2; P[h * 4 + 2] = u1; P[h * 4 + 3] = u2;
        if (h == 0) {
            float c = linb[0];
            for (int f = 0; f < 128; f++) c += (linW[f] + linW[128 + f]) * bb[f];
            *biasC = c;
        }
    } else if (b < 6703) {
        int i = (b - 6507) * 256 + t;
        if (i < NPROT) cnt[i] = 0;
    } else {
        int i = (b - 6703) * 256 + t;     // 782 blocks cover 50048*4 exactly
        if (i < NPROT_PAD * 4) y[i] = 0.f;
    }
}

// ---------- layer-1 neighbor mean (bf16 gather from A own-halves) ----------
__global__ void k_agg(const int* __restrict__ rowptr, const int* __restrict__ ssrc,
                      const float* __restrict__ inv, __bf16* __restrict__ A) {
    int wave = threadIdx.x >> 6, lane = threadIdx.x & 63;
    int half = lane >> 5, sl = lane & 31;
    int node = blockIdx.x * 8 + wave * 2 + half;
    if (node >= NPROT) return;
    int b0 = rowptr[node], b1 = rowptr[node + 1];
    float a0 = 0.f, a1 = 0.f, a2 = 0.f, a3 = 0.f;
    const __bf16* base = A + 128 + (size_t)sl * 4;   // own-half source
    for (int j = b0; j < b1; j++) {
        int s = ssrc[j];
        bf16x4 v = *(const bf16x4*)(base + (size_t)s * 256);
        a0 += (float)v[0]; a1 += (float)v[1]; a2 += (float)v[2]; a3 += (float)v[3];
    }
    float iv = inv[node];
    bf16x4 o;
    o[0] = (__bf16)(a0 * iv); o[1] = (__bf16)(a1 * iv);
    o[2] = (__bf16)(a2 * iv); o[3] = (__bf16)(a3 * iv);
    *(bf16x4*)(A + (size_t)node * 256 + sl * 4) = o;
}

// ---------- GEMM z = A @ Bw^T (+ab), relu, project onto P -> atomicAdd y[node][4] ----------
// LDS-staged B: 128 cols x 128 k-chunk, stride 136 bf16 (16B-aligned, balanced banks).
#define BST 136
__global__ __launch_bounds__(256, 4) void k_gemm(const __bf16* __restrict__ A,
                                                 const __bf16* __restrict__ Bw,
                                                 const float* __restrict__ ab,
                                                 const float* __restrict__ P,
                                                 float* __restrict__ y) {
    __shared__ __bf16 Bs[128 * BST];
    int tid = threadIdx.x;
    int ch = blockIdx.y;                       // column half (128 cols each)
    int wave = tid >> 6, lane = tid & 63;
    int r = lane & 15, quad = lane >> 4;
    int row0 = blockIdx.x * 128 + wave * 32;

    floatx4 acc[2][8];
#pragma unroll
    for (int g = 0; g < 2; g++)
#pragma unroll
        for (int t = 0; t < 8; t++) acc[g][t] = (floatx4){0.f, 0.f, 0.f, 0.f};

    const __bf16* A0 = A + (size_t)(row0 + r) * 256 + quad * 8;
    const __bf16* Bp = Bs + (size_t)r * BST + quad * 8;
    int sc = tid >> 1, sh = tid & 1;           // staging: thread -> (col, k-half of chunk)
    const __bf16* gsrc = Bw + (size_t)(ch * 128 + sc) * 256 + sh * 64;
    __bf16* ldst = Bs + (size_t)sc * BST + sh * 64;

    for (int chunk = 0; chunk < 2; chunk++) {
#pragma unroll
        for (int i = 0; i < 8; i++)
            *(bf16x8*)(ldst + i * 8) = *(const bf16x8*)(gsrc + chunk * 128 + i * 8);
        __syncthreads();
#pragma unroll
        for (int kk = 0; kk < 4; kk++) {
            bf16x8 af0 = *(const bf16x8*)(A0 + chunk * 128 + kk * 32);
            bf16x8 af1 = *(const bf16x8*)(A0 + 16 * 256 + chunk * 128 + kk * 32);
#pragma unroll
            for (int t = 0; t < 8; t++) {
                bf16x8 bf = *(const bf16x8*)(Bp + (size_t)t * 16 * BST + kk * 32);
                acc[0][t] = __builtin_amdgcn_mfma_f32_16x16x32_bf16(af0, bf, acc[0][t], 0, 0, 0);
                acc[1][t] = __builtin_amdgcn_mfma_f32_16x16x32_bf16(af1, bf, acc[1][t], 0, 0, 0);
            }
        }
        __syncthreads();
    }

    // epilogue: h = relu(z + ab[col]); partial projection onto P; atomicAdd into y
#pragma unroll
    for (int g = 0; g < 2; g++) {
        float part[4][4] = {{0.f}};
#pragma unroll
        for (int t = 0; t < 8; t++) {
            int col = ch * 128 + t * 16 + r;
            float bias = ab[col];
            float4 pv = *(const float4*)(P + col * 4);
#pragma unroll
            for (int rr = 0; rr < 4; rr++) {
                float h = acc[g][t][rr] + bias;
                h = h > 0.f ? h : 0.f;
                part[rr][0] += h * pv.x; part[rr][1] += h * pv.y;
                part[rr][2] += h * pv.z; part[rr][3] += h * pv.w;
            }
        }
#pragma unroll
        for (int m = 1; m < 16; m <<= 1)
#pragma unroll
            for (int rr = 0; rr < 4; rr++)
#pragma unroll
                for (int j = 0; j < 4; j++)
                    part[rr][j] += __shfl_xor(part[rr][j], m, 64);
        if (r == 0) {
#pragma unroll
            for (int rr = 0; rr < 4; rr++) {
                int row = row0 + g * 16 + quad * 4 + rr;
                float* yp = y + (size_t)row * 4;
                atomicAdd(yp + 0, part[rr][0]);
                atomicAdd(yp + 1, part[rr][1]);
                atomicAdd(yp + 2, part[rr][2]);
                atomicAdd(yp + 3, part[rr][3]);
            }
        }
    }
}

// ---------- head: per masked node, CSR-sum scalar projections ----------
__global__ void k_head(const int* __restrict__ mask, const int* __restrict__ rowptr,
                       const int* __restrict__ ssrc, const float* __restrict__ inv,
                       const float* __restrict__ y, const float* __restrict__ biasC,
                       float* __restrict__ out) {
    int tid = blockIdx.x * 256 + threadIdx.x;
    int p = tid >> 1, side = tid & 1;
    float res = 0.f;
    if (p < NPAIR) {
        int node = mask[p * 2 + side];
        int b0 = rowptr[node], b1 = rowptr[node + 1];
        float s = 0.f;
        for (int j = b0; j < b1; j++) s += y[(size_t)ssrc[j] * 4 + side];
        res = s * inv[node] + y[(size_t)node * 4 + 2 + side];
    }
    float other = __shfl_xor(res, 1, 64);
    if (p < NPAIR && side == 0) {
        float z = res + other + *biasC;
        out[p] = 1.f / (1.f + expf(-z));
    }
}

extern "C" void kernel_launch(void* const* d_in, const int* in_sizes, int n_in,
                              void* d_out, int out_size, void* d_ws, size_t ws_size,
                              hipStream_t stream) {
    const float* x_protein = (const float*)d_in[0];
    const float* a_ppi_Wl  = (const float*)d_in[11];
    const float* a_ppi_b   = (const float*)d_in[12];
    const float* a_ppi_Wr  = (const float*)d_in[13];
    const float* b_ppi_Wl  = (const float*)d_in[23];
    const float* b_ppi_b   = (const float*)d_in[24];
    const float* b_ppi_Wr  = (const float*)d_in[25];
    const float* lin_W     = (const float*)d_in[26];
    const float* lin_b     = (const float*)d_in[27];
    const int* ppi_src     = (const int*)d_in[34];
    const int* ppi_dst     = (const int*)d_in[35];
    const int* mask        = (const int*)d_in[36];
    float* out = (float*)d_out;

    char* ws = (char*)d_ws;
    size_t o = 0;
    auto alloc = [&](size_t n) -> char* {
        char* r = ws + o;
        o = (o + n + 511) & ~(size_t)511;
        return r;
    };
    int*    cnt      = (int*)alloc((size_t)NPROT * 4);
    int*    rowptr   = (int*)alloc((size_t)(NPROT + 1) * 4);
    int*    cursor   = (int*)alloc((size_t)NPROT * 4);
    int*    blocksum = (int*)alloc(64 * 4);
    float*  inv      = (float*)alloc((size_t)NPROT * 4);
    int*    ssrc     = (int*)alloc((size_t)EPPI * 4);
    __bf16* A        = (__bf16*)alloc((size_t)NPROT_PAD * 256 * 2);
    __bf16* Bw       = (__bf16*)alloc(256 * 256 * 2);
    float*  P        = (float*)alloc(256 * 4 * 4);
    float*  biasC    = (float*)alloc(4);
    float*  y        = (float*)alloc((size_t)NPROT_PAD * 4 * 4);
    (void)ws_size;

    int nb = (NPROT + 1023) / 1024;  // 49

    k_prep<<<7485, 256, 0, stream>>>(x_protein, a_ppi_Wl, a_ppi_Wr, lin_W, lin_b,
                                     b_ppi_Wl, b_ppi_Wr, b_ppi_b,
                                     A, Bw, P, biasC, cnt, y);
    k_hist<<<(EPPI + 255) / 256, 256, 0, stream>>>(ppi_dst, cnt);
    k_scan1<<<nb, 1024, 0, stream>>>(cnt, rowptr, blocksum);
    k_scan2<<<1, 64, 0, stream>>>(blocksum, nb);
    k_scan3<<<nb, 1024, 0, stream>>>(cnt, rowptr, cursor, inv, blocksum);
    k_fill<<<(EPPI + 255) / 256, 256, 0, stream>>>(ppi_src, ppi_dst, cursor, ssrc);
    k_agg<<<(NPROT + 7) / 8, 256, 0, stream>>>(rowptr, ssrc, inv, A);
    dim3 ggrid((NPROT_PAD + 127) / 128, 2);
    k_gemm<<<ggrid, 256, 0, stream>>>(A, Bw, a_ppi_b, P, y);
    k_head<<<(2 * NPAIR + 255) / 256, 256, 0, stream>>>(mask, rowptr, ssrc, inv, y, biasC, out);
}

// Round 3
// 272.756 us; speedup vs baseline: 1.2967x; 1.1250x over previous
//
#include <hip/hip_runtime.h>
#include <math.h>

#define NPROT 50000
#define NPROT_PAD 50048
#define EPPI 500000
#define NPAIR 4096

typedef __attribute__((ext_vector_type(8))) __bf16 bf16x8;
typedef __attribute__((ext_vector_type(4))) __bf16 bf16x4;
typedef __attribute__((ext_vector_type(4))) float floatx4;

// ---------- CSR build ----------
__global__ void k_hist(const int* __restrict__ dst, int* __restrict__ cnt) {
    int e = blockIdx.x * 256 + threadIdx.x;
    if (e < EPPI) atomicAdd(&cnt[dst[e]], 1);
}

__global__ void k_scan1(const int* __restrict__ cnt, int* __restrict__ rowptr,
                        int* __restrict__ blocksum) {
    __shared__ int sd[1024];
    int t = threadIdx.x;
    int i = blockIdx.x * 1024 + t;
    int v = (i < NPROT) ? cnt[i] : 0;
    sd[t] = v;
    __syncthreads();
    int x = v;
    for (int off = 1; off < 1024; off <<= 1) {
        int add = (t >= off) ? sd[t - off] : 0;
        __syncthreads();
        x += add;
        sd[t] = x;
        __syncthreads();
    }
    if (i < NPROT) rowptr[i] = x - v;   // block-local exclusive
    if (t == 1023) blocksum[blockIdx.x] = x;
}

__global__ void k_scan2(int* blocksum, int nb) {
    if (threadIdx.x == 0 && blockIdx.x == 0) {
        int run = 0;
        for (int b = 0; b < nb; b++) { int t = blocksum[b]; blocksum[b] = run; run += t; }
    }
}

__global__ void k_scan3(const int* __restrict__ cnt, int* __restrict__ rowptr,
                        int* __restrict__ cursor, float* __restrict__ inv,
                        const int* __restrict__ blocksum) {
    int t = threadIdx.x;
    int i = blockIdx.x * 1024 + t;
    if (i < NPROT) {
        int r = rowptr[i] + blocksum[blockIdx.x];
        rowptr[i] = r;
        cursor[i] = r;
        int c = cnt[i];
        inv[i] = 1.0f / (float)(c > 1 ? c : 1);
        if (i == NPROT - 1) rowptr[NPROT] = r + c;
    }
}

__global__ void k_fill(const int* __restrict__ src, const int* __restrict__ dst,
                       int* __restrict__ cursor, int* __restrict__ ssrc) {
    int e = blockIdx.x * 256 + threadIdx.x;
    if (e < EPPI) {
        int d = dst[e];
        int p = atomicAdd(&cursor[d], 1);
        ssrc[p] = src[e];
    }
}

// ---------- fused prep: x->bf16 own-half of A, Bw build, P/biasC, zero cnt ----------
__global__ void k_prep(const float* __restrict__ x,
                       const float* __restrict__ Wl, const float* __restrict__ Wr,
                       const float* __restrict__ linW, const float* __restrict__ linb,
                       const float* __restrict__ bWl, const float* __restrict__ bWr,
                       const float* __restrict__ bb,
                       __bf16* __restrict__ A, __bf16* __restrict__ Bw,
                       float* __restrict__ P, float* __restrict__ biasC,
                       int* __restrict__ cnt) {
    int b = blockIdx.x, t = threadIdx.x;
    if (b < 6250) {
        // cast x rows into A[row][128..255]
        int i = b * 256 + t;              // float4 index over 50000*32
        int row = i >> 5, k4 = (i & 31) << 2;
        float4 v = *(const float4*)(x + (size_t)row * 128 + k4);
        bf16x4 o; o[0] = (__bf16)v.x; o[1] = (__bf16)v.y; o[2] = (__bf16)v.z; o[3] = (__bf16)v.w;
        *(bf16x4*)(A + (size_t)row * 256 + 128 + k4) = o;
    } else if (b < 6506) {
        // Bw[h][k]: k<128 -> aWl, else aWr  (bf16)
        int idx = (b - 6250) * 256 + t;   // 65536
        int h = idx >> 8, k = idx & 255;
        float v = (k < 128) ? Wl[h * 128 + k] : Wr[h * 128 + (k - 128)];
        Bw[idx] = (__bf16)v;
    } else if (b == 6506) {
        int h = t;  // 256
        float v1 = 0, v2 = 0, u1 = 0, u2 = 0;
        for (int f = 0; f < 128; f++) {
            float w1 = linW[f], w2 = linW[128 + f];
            float wl = bWl[f * 256 + h], wr = bWr[f * 256 + h];
            v1 += w1 * wl; v2 += w2 * wl; u1 += w1 * wr; u2 += w2 * wr;
        }
        P[h * 4 + 0] = v1; P[h * 4 + 1] = v2; P[h * 4 + 2] = u1; P[h * 4 + 3] = u2;
        if (h == 0) {
            float c = linb[0];
            for (int f = 0; f < 128; f++) c += (linW[f] + linW[128 + f]) * bb[f];
            *biasC = c;
        }
    } else {
        int i = (b - 6507) * 256 + t;
        if (i < NPROT) cnt[i] = 0;
    }
}

// ---------- layer-1 neighbor mean (bf16 gather from A own-halves) ----------
// quarter-wave (16 lanes x bf16x8) per node, unroll-4 for load-level parallelism
__global__ void k_agg(const int* __restrict__ rowptr, const int* __restrict__ ssrc,
                      const float* __restrict__ inv, __bf16* __restrict__ A) {
    int wave = threadIdx.x >> 6, lane = threadIdx.x & 63;
    int q = lane >> 4, sl = lane & 15;
    int node = blockIdx.x * 16 + wave * 4 + q;
    if (node >= NPROT) return;
    int b0 = rowptr[node], b1 = rowptr[node + 1];
    float a[8];
#pragma unroll
    for (int e = 0; e < 8; e++) a[e] = 0.f;
    const __bf16* base = A + 128 + (size_t)sl * 8;   // own-half source
    int j = b0;
    for (; j + 4 <= b1; j += 4) {
        int s0 = ssrc[j], s1 = ssrc[j + 1], s2 = ssrc[j + 2], s3 = ssrc[j + 3];
        bf16x8 v0 = *(const bf16x8*)(base + (size_t)s0 * 256);
        bf16x8 v1 = *(const bf16x8*)(base + (size_t)s1 * 256);
        bf16x8 v2 = *(const bf16x8*)(base + (size_t)s2 * 256);
        bf16x8 v3 = *(const bf16x8*)(base + (size_t)s3 * 256);
#pragma unroll
        for (int e = 0; e < 8; e++)
            a[e] += ((float)v0[e] + (float)v1[e]) + ((float)v2[e] + (float)v3[e]);
    }
    for (; j < b1; j++) {
        int s = ssrc[j];
        bf16x8 v = *(const bf16x8*)(base + (size_t)s * 256);
#pragma unroll
        for (int e = 0; e < 8; e++) a[e] += (float)v[e];
    }
    float iv = inv[node];
    bf16x8 o;
#pragma unroll
    for (int e = 0; e < 8; e++) o[e] = (__bf16)(a[e] * iv);
    *(bf16x8*)(A + (size_t)node * 256 + sl * 8) = o;
}

// ---------- GEMM z = A @ Bw^T (+ab), relu, project onto P -> y[node][4] ----------
// 64 rows/block (16/wave). A fragments register-resident (loaded once).
// B staged per 64-col chunk in PERMUTED fragment-major LDS layout:
//   group g = (t*8+kk)*64 + lane  holds  Bw[chunk*64 + t*16 + (g&15)][kk*32 + ((g>>4)&3)*8 ..+8]
// -> every ds_read_b128 and ds_write_b128 is lane-linear: zero bank conflicts.
__global__ __launch_bounds__(256) void k_gemm(const __bf16* __restrict__ A,
                                              const __bf16* __restrict__ Bw,
                                              const float* __restrict__ ab,
                                              const float* __restrict__ P,
                                              float* __restrict__ y) {
    __shared__ __bf16 Bs[2048 * 8];   // 32 KB
    int tid = threadIdx.x;
    int wave = tid >> 6, lane = tid & 63;
    int r = lane & 15, quad = lane >> 4;
    int row0 = blockIdx.x * 64 + wave * 16;

    // load A fragments once (8 k-chunks of 32)
    bf16x8 areg[8];
    const __bf16* Ap = A + (size_t)(row0 + r) * 256 + quad * 8;
#pragma unroll
    for (int kk = 0; kk < 8; kk++) areg[kk] = *(const bf16x8*)(Ap + kk * 32);

    float part[4][4] = {{0.f}};

    for (int chunk = 0; chunk < 4; chunk++) {
        if (chunk) __syncthreads();
#pragma unroll
        for (int jj = 0; jj < 8; jj++) {
            int g = jj * 256 + tid;
            int gr = g & 15, gq = (g >> 4) & 3;
            int gkk = (g >> 6) & 7;
            int gt = g >> 9;
            const __bf16* src = Bw + (size_t)(chunk * 64 + gt * 16 + gr) * 256 + gkk * 32 + gq * 8;
            *(bf16x8*)(Bs + (size_t)g * 8) = *(const bf16x8*)src;
        }
        __syncthreads();

        floatx4 acc[4];
#pragma unroll
        for (int t = 0; t < 4; t++) acc[t] = (floatx4){0.f, 0.f, 0.f, 0.f};
#pragma unroll
        for (int kk = 0; kk < 8; kk++) {
#pragma unroll
            for (int t = 0; t < 4; t++) {
                bf16x8 bf = *(const bf16x8*)(Bs + (size_t)((t * 8 + kk) * 64 + lane) * 8);
                acc[t] = __builtin_amdgcn_mfma_f32_16x16x32_bf16(areg[kk], bf, acc[t], 0, 0, 0);
            }
        }

        // epilogue: h = relu(z + ab[col]); accumulate projection onto P
#pragma unroll
        for (int t = 0; t < 4; t++) {
            int col = chunk * 64 + t * 16 + r;
            float bias = ab[col];
            float4 pv = *(const float4*)(P + col * 4);
#pragma unroll
            for (int rr = 0; rr < 4; rr++) {
                float h = acc[t][rr] + bias;
                h = h > 0.f ? h : 0.f;
                part[rr][0] += h * pv.x; part[rr][1] += h * pv.y;
                part[rr][2] += h * pv.z; part[rr][3] += h * pv.w;
            }
        }
    }

    // reduce over the 16 col-lanes (r); store 16 rows per wave directly
#pragma unroll
    for (int m = 1; m < 16; m <<= 1)
#pragma unroll
        for (int rr = 0; rr < 4; rr++)
#pragma unroll
            for (int j = 0; j < 4; j++)
                part[rr][j] += __shfl_xor(part[rr][j], m, 64);
    if (r == 0) {
#pragma unroll
        for (int rr = 0; rr < 4; rr++) {
            int row = row0 + quad * 4 + rr;
            float4 o;
            o.x = part[rr][0]; o.y = part[rr][1]; o.z = part[rr][2]; o.w = part[rr][3];
            *(float4*)(y + (size_t)row * 4) = o;
        }
    }
}

// ---------- head: per masked node, CSR-sum scalar projections ----------
__global__ void k_head(const int* __restrict__ mask, const int* __restrict__ rowptr,
                       const int* __restrict__ ssrc, const float* __restrict__ inv,
                       const float* __restrict__ y, const float* __restrict__ biasC,
                       float* __restrict__ out) {
    int tid = blockIdx.x * 256 + threadIdx.x;
    int p = tid >> 1, side = tid & 1;
    float res = 0.f;
    if (p < NPAIR) {
        int node = mask[p * 2 + side];
        int b0 = rowptr[node], b1 = rowptr[node + 1];
        float s = 0.f;
        for (int j = b0; j < b1; j++) s += y[(size_t)ssrc[j] * 4 + side];
        res = s * inv[node] + y[(size_t)node * 4 + 2 + side];
    }
    float other = __shfl_xor(res, 1, 64);
    if (p < NPAIR && side == 0) {
        float z = res + other + *biasC;
        out[p] = 1.f / (1.f + expf(-z));
    }
}

extern "C" void kernel_launch(void* const* d_in, const int* in_sizes, int n_in,
                              void* d_out, int out_size, void* d_ws, size_t ws_size,
                              hipStream_t stream) {
    const float* x_protein = (const float*)d_in[0];
    const float* a_ppi_Wl  = (const float*)d_in[11];
    const float* a_ppi_b   = (const float*)d_in[12];
    const float* a_ppi_Wr  = (const float*)d_in[13];
    const float* b_ppi_Wl  = (const float*)d_in[23];
    const float* b_ppi_b   = (const float*)d_in[24];
    const float* b_ppi_Wr  = (const float*)d_in[25];
    const float* lin_W     = (const float*)d_in[26];
    const float* lin_b     = (const float*)d_in[27];
    const int* ppi_src     = (const int*)d_in[34];
    const int* ppi_dst     = (const int*)d_in[35];
    const int* mask        = (const int*)d_in[36];
    float* out = (float*)d_out;

    char* ws = (char*)d_ws;
    size_t o = 0;
    auto alloc = [&](size_t n) -> char* {
        char* r = ws + o;
        o = (o + n + 511) & ~(size_t)511;
        return r;
    };
    int*    cnt      = (int*)alloc((size_t)NPROT * 4);
    int*    rowptr   = (int*)alloc((size_t)(NPROT + 1) * 4);
    int*    cursor   = (int*)alloc((size_t)NPROT * 4);
    int*    blocksum = (int*)alloc(64 * 4);
    float*  inv      = (float*)alloc((size_t)NPROT * 4);
    int*    ssrc     = (int*)alloc((size_t)EPPI * 4);
    __bf16* A        = (__bf16*)alloc((size_t)NPROT_PAD * 256 * 2);
    __bf16* Bw       = (__bf16*)alloc(256 * 256 * 2);
    float*  P        = (float*)alloc(256 * 4 * 4);
    float*  biasC    = (float*)alloc(4);
    float*  y        = (float*)alloc((size_t)NPROT_PAD * 4 * 4);
    (void)ws_size;

    int nb = (NPROT + 1023) / 1024;  // 49

    k_prep<<<6703, 256, 0, stream>>>(x_protein, a_ppi_Wl, a_ppi_Wr, lin_W, lin_b,
                                     b_ppi_Wl, b_ppi_Wr, b_ppi_b,
                                     A, Bw, P, biasC, cnt);
    k_hist<<<(EPPI + 255) / 256, 256, 0, stream>>>(ppi_dst, cnt);
    k_scan1<<<nb, 1024, 0, stream>>>(cnt, rowptr, blocksum);
    k_scan2<<<1, 64, 0, stream>>>(blocksum, nb);
    k_scan3<<<nb, 1024, 0, stream>>>(cnt, rowptr, cursor, inv, blocksum);
    k_fill<<<(EPPI + 255) / 256, 256, 0, stream>>>(ppi_src, ppi_dst, cursor, ssrc);
    k_agg<<<(NPROT + 15) / 16, 256, 0, stream>>>(rowptr, ssrc, inv, A);
    k_gemm<<<(NPROT_PAD + 63) / 64, 256, 0, stream>>>(A, Bw, a_ppi_b, P, y);
    k_head<<<(2 * NPAIR + 255) / 256, 256, 0, stream>>>(mask, rowptr, ssrc, inv, y, biasC, out);
}